// Round 18
// baseline (342.862 us; speedup 1.0000x reference)
//
#include <hip/hip_runtime.h>
#include <hip/hip_fp16.h>

#define NN 20000
#define EE 320000
#define ETOT 340000
#define FIN 128
#define NH 6
#define FF 384
#define NOUT 10
#define NG 64
#define NEG 0.2f
#define PCH 32
#define NB ((NN + 255) / 256)
#define NBLK ((NN + 3) / 4)
#define TBLOFF (NN * 192)   // dword offset between g_h16[0] and g_h16[1] rows

typedef short short8 __attribute__((ext_vector_type(8)));
typedef float f32x4 __attribute__((ext_vector_type(4)));

// ---------------- static device storage (avoids ws_size dependence) ----------
__device__ __half g_h16[2][(size_t)NN * FF];          // per-branch h tables (contiguous)
__device__ unsigned short g_feat[2][(size_t)NN * FF]; // bf16 L1-out, reused as L2-out
__device__ unsigned short g_xHi[(size_t)NN * FIN];
__device__ unsigned short g_WtHi[4][FF * FF];  // transposed weights [col][k]
__device__ float g_alS[4][NN * NH];            // per-layer alpha_src (atomic acc)
__device__ float g_alD[4][NN * NH];
__device__ int g_rowptr[NN + 1];
__device__ int g_cnt[NN];
__device__ int g_cur[NN];
__device__ int g_blocksum[NB];
__device__ int g_colsrc[ETOT];
__device__ float g_pool[NG * FF];
__device__ int g_gcnt[NG];

// ---------------- helpers ----------------------------------------------------
__device__ __forceinline__ unsigned short f2bf(float f) {
  unsigned u = __float_as_uint(f);
  u += 0x7FFFu + ((u >> 16) & 1u);
  return (unsigned short)(u >> 16);
}
__device__ __forceinline__ float bf2f(unsigned short s) {
  return __uint_as_float(((unsigned)s) << 16);
}

__device__ __forceinline__ void gl_lds16(const void* g, void* l) {
  __builtin_amdgcn_global_load_lds(
      (const __attribute__((address_space(1))) unsigned int*)(unsigned long long)g,
      (__attribute__((address_space(3))) unsigned int*)(unsigned int)(unsigned long long)l,
      16, 0, 0);
}

__device__ __forceinline__ void mfma_acc(f32x4& c, short8 a, short8 b) {
  asm("v_mfma_f32_16x16x32_bf16 %0, %1, %2, %0" : "+v"(c) : "v"(a), "v"(b));
}

// fp16-source FMA into f32 acc: acc.x += f16lo(hv)*w ; acc.y += f16hi(hv)*w
__device__ __forceinline__ void fmix(float2& acc, unsigned hv, float w) {
  asm("v_fma_mix_f32 %0, %2, %3, %0 op_sel:[0,0,0] op_sel_hi:[1,0,0]\n\t"
      "v_fma_mix_f32 %1, %2, %3, %1 op_sel:[1,0,0] op_sel_hi:[1,0,0]"
      : "+v"(acc.x), "+v"(acc.y)
      : "v"(hv), "v"(w));
}

// ---------------- merged prep: weight bf16-transpose + zeroing + x->bf16 -----
__global__ __launch_bounds__(256) void k_prep(const float* __restrict__ xin,
                                              const float* __restrict__ Ws1,
                                              const float* __restrict__ Ws2,
                                              const float* __restrict__ W1,
                                              const float* __restrict__ W2) {
  const int tid = blockIdx.x * 256 + threadIdx.x;
  const int stride = gridDim.x * 256;
  for (int i = tid; i < FIN * FF; i += stride) {
    int k = i / FF, c = i % FF;
    g_WtHi[0][c * FIN + k] = f2bf(Ws1[i]);
    g_WtHi[2][c * FIN + k] = f2bf(W1[i]);
  }
  for (int i = tid; i < FF * FF; i += stride) {
    int k = i / FF, c = i % FF;
    g_WtHi[1][c * FF + k] = f2bf(Ws2[i]);
    g_WtHi[3][c * FF + k] = f2bf(W2[i]);
  }
  for (int i = tid; i < NN; i += stride) g_cnt[i] = 0;
  for (int i = tid; i < NG * FF; i += stride) g_pool[i] = 0.f;
  for (int i = tid; i < NG; i += stride) g_gcnt[i] = 0;
  for (int i = tid; i < 4 * NN * NH; i += stride) {
    (&g_alS[0][0])[i] = 0.f;
    (&g_alD[0][0])[i] = 0.f;
  }
  const float4* s4 = (const float4*)xin;
  ushort4* oh4 = (ushort4*)g_xHi;
  for (int i = tid; i < (NN * FIN) >> 2; i += stride) {
    float4 v = s4[i];
    ushort4 h;
    h.x = f2bf(v.x); h.y = f2bf(v.y); h.z = f2bf(v.z); h.w = f2bf(v.w);
    oh4[i] = h;
  }
}

__global__ __launch_bounds__(256) void k_hist(const int* __restrict__ ei) {
  int i = blockIdx.x * 256 + threadIdx.x;
  if (i >= ETOT) return;
  int d = (i < EE) ? ei[EE + i] : (i - EE);
  atomicAdd(&g_cnt[d], 1);
}

// ---------------- hierarchical scan (3 launches, shuffle-based) --------------
__global__ __launch_bounds__(256) void k_scan_blk() {
  int b = blockIdx.x;
  int tid = threadIdx.x;
  int i = b * 256 + tid;
  int lane = tid & 63, wid = tid >> 6;
  int v = (i < NN) ? g_cnt[i] : 0;
  int s = v;
  #pragma unroll
  for (int off = 1; off < 64; off <<= 1) {
    int t = __shfl_up(s, off);
    if (lane >= off) s += t;
  }
  __shared__ int wsum[4];
  if (lane == 63) wsum[wid] = s;
  __syncthreads();
  int woff = 0;
  #pragma unroll
  for (int w = 0; w < 4; ++w) woff += (w < wid) ? wsum[w] : 0;
  if (i < NN) g_rowptr[i] = woff + s - v;   // block-local exclusive
  if (tid == 0) g_blocksum[b] = wsum[0] + wsum[1] + wsum[2] + wsum[3];
}

__global__ __launch_bounds__(128) void k_scan_top() {
  int tid = threadIdx.x;
  int lane = tid & 63, wid = tid >> 6;
  int v = (tid < NB) ? g_blocksum[tid] : 0;
  int s = v;
  #pragma unroll
  for (int off = 1; off < 64; off <<= 1) {
    int t = __shfl_up(s, off);
    if (lane >= off) s += t;
  }
  __shared__ int wsum[2];
  if (lane == 63) wsum[wid] = s;
  __syncthreads();
  int woff = (wid == 1) ? wsum[0] : 0;
  int excl = woff + s - v;
  if (tid < NB) g_blocksum[tid] = excl;
  if (tid == NB - 1) g_rowptr[NN] = excl + v;
}

__global__ __launch_bounds__(256) void k_scan_add() {
  int i = blockIdx.x * 256 + threadIdx.x;
  if (i >= NN) return;
  int r = g_rowptr[i] + g_blocksum[blockIdx.x];
  g_rowptr[i] = r;
  g_cur[i] = r;
}

__global__ __launch_bounds__(256) void k_scatter(const int* __restrict__ ei) {
  int i = blockIdx.x * 256 + threadIdx.x;
  if (i >= ETOT) return;
  int s, d;
  if (i < EE) { s = ei[i]; d = ei[EE + i]; } else { s = d = i - EE; }
  int pos = atomicAdd(&g_cur[d], 1);
  g_colsrc[pos] = s;
}

// ---------------- GEMM: h16[br] = A @ WtHi^T (single-term bf16, fp32 acc) ----
// both branches of one level in one launch (blockIdx.z = branch).
// epilogue: fused alpha partials (each wave's 64-col stripe = one head).
__global__ __launch_bounds__(256) void k_gemm(int lvl,
                                              const float* __restrict__ asr0,
                                              const float* __restrict__ adt0,
                                              const float* __restrict__ asr1,
                                              const float* __restrict__ adt1) {
  __shared__ unsigned short lA[128 * 64];
  __shared__ unsigned short lB[128 * 64];
  const int br = blockIdx.z;
  const int layer = (lvl ? 1 : 0) + (br ? 2 : 0);
  const int widx = layer;                 // 0=Ws1,1=Ws2,2=W1,3=W2
  const int K = lvl ? FF : FIN;
  const unsigned short* Ah = lvl ? g_feat[br] : g_xHi;
  const unsigned short* Bh = g_WtHi[widx];
  const float* asr = br ? asr1 : asr0;
  const float* adt = br ? adt1 : adt0;
  __half* hout = g_h16[br];
  const int m0 = blockIdx.x * 128;
  const int n0 = blockIdx.y * 128;
  const int tid = threadIdx.x;
  const int wave = tid >> 6, lane = tid & 63;
  const int wm = wave >> 1, wn = wave & 1;
  const int srow = lane >> 3;        // row within 8-row chunk
  const int scol = (lane & 7) * 8;   // k-element offset

  f32x4 acc[4][4] = {};

  for (int k0 = 0; k0 < K; k0 += 64) {
    __syncthreads();  // prior reads done before overwrite
    #pragma unroll
    for (int it = 0; it < 4; ++it) {
      int c = wave * 4 + it;
      int rA = c * 8 + srow;
      int gr = m0 + rA; gr = (gr < NN) ? gr : (NN - 1);
      gl_lds16(Ah + (size_t)gr * K + k0 + scol, (unsigned short*)lA + c * 512);
      int cB = n0 + rA;  // always < 384
      gl_lds16(Bh + (size_t)cB * K + k0 + scol, (unsigned short*)lB + c * 512);
    }
    __syncthreads();  // drains vmcnt for global_load_lds
    #pragma unroll
    for (int kk = 0; kk < 64; kk += 32) {
      const int kb = kk + (lane >> 4) * 8;
      const int r16 = lane & 15;
      short8 af[4], bfr[4];
      #pragma unroll
      for (int mf = 0; mf < 4; ++mf)
        af[mf] = *(const short8*)&lA[(wm * 64 + mf * 16 + r16) * 64 + kb];
      #pragma unroll
      for (int nf = 0; nf < 4; ++nf)
        bfr[nf] = *(const short8*)&lB[(wn * 64 + nf * 16 + r16) * 64 + kb];
      #pragma unroll
      for (int mf = 0; mf < 4; ++mf)
        #pragma unroll
        for (int nf = 0; nf < 4; ++nf)
          mfma_acc(acc[mf][nf], af[mf], bfr[nf]);
    }
  }
  asm volatile("s_nop 7\n\ts_nop 7" :::);

  const int r16 = lane & 15;
  // ---- C-write (fp16 table) ----
  #pragma unroll
  for (int mf = 0; mf < 4; ++mf) {
    #pragma unroll
    for (int nf = 0; nf < 4; ++nf) {
      int col = n0 + wn * 64 + nf * 16 + r16;
      int rb = m0 + wm * 64 + mf * 16 + ((lane >> 4) << 2);
      #pragma unroll
      for (int j = 0; j < 4; ++j) {
        int r = rb + j;
        if (r < NN) hout[(size_t)r * FF + col] = __float2half(acc[mf][nf][j]);
      }
    }
  }
  // ---- fused alpha partials: head = by*2 + wn ----
  const int hd = blockIdx.y * 2 + wn;
  float as_v[4], ad_v[4];
  #pragma unroll
  for (int nf = 0; nf < 4; ++nf) {
    as_v[nf] = asr[hd * 64 + nf * 16 + r16];
    ad_v[nf] = adt[hd * 64 + nf * 16 + r16];
  }
  float* alS = g_alS[layer];
  float* alD = g_alD[layer];
  #pragma unroll
  for (int mf = 0; mf < 4; ++mf) {
    #pragma unroll
    for (int j = 0; j < 4; ++j) {
      float ps = 0.f, pd = 0.f;
      #pragma unroll
      for (int nf = 0; nf < 4; ++nf) {
        ps = fmaf(acc[mf][nf][j], as_v[nf], ps);
        pd = fmaf(acc[mf][nf][j], ad_v[nf], pd);
      }
      #pragma unroll
      for (int off = 1; off < 16; off <<= 1) {
        ps += __shfl_xor(ps, off);
        pd += __shfl_xor(pd, off);
      }
      int r = m0 + wm * 64 + mf * 16 + ((lane >> 4) << 2) + j;
      if (r16 == 0 && r < NN) {
        atomicAdd(&alS[r * NH + hd], ps);
        atomicAdd(&alD[r * NH + hd], pd);
      }
    }
  }
}

// ---------------- softmax + aggregation, one wave per node, BOTH branches ----
// pass 1: lane-parallel softmax for both branches (shared edge sources);
// per-head f32 weights staged in per-wave LDS. pass 2: ONE address per edge,
// branch-1 row read at compile-time dword offset TBLOFF; x4 unroll, tail-free.
// lvl 0: out -> g_feat[b] (GEMM input). lvl 1: out -> g_feat[b] (pool input).
__global__ __launch_bounds__(256) void k_edge(int lvl,
                                              const float* __restrict__ bias0,
                                              const float* __restrict__ bias1) {
  __shared__ int l_se[4][64];
  __shared__ float l_wf[4][2][NH][64];
  int wv = threadIdx.x >> 6;
  int node = blockIdx.x * 4 + wv;
  int lane = threadIdx.x & 63;
  if (node >= NN) return;
  const int lo = g_rowptr[node], hi = g_rowptr[node + 1];
  const int deg = hi - lo;
  const bool hiHalf = (lane >= 32);
  const bool fast = (deg <= 64);
  float m[2][NH], inv[2][NH];   // slow-path state

  if (fast) {
    bool val = lane < deg;
    int s = val ? g_colsrc[lo + lane] : 0;
    l_se[wv][lane] = s;
    #pragma unroll
    for (int b = 0; b < 2; ++b) {
      const int layer = (lvl ? 1 : 0) + (b ? 2 : 0);
      const float* aS = g_alS[layer];
      const float* aD = g_alD[layer] + (size_t)node * NH;
      const float2* ap = (const float2*)(aS + (size_t)s * NH);
      float2 p0 = ap[0], p1 = ap[1], p2 = ap[2];
      float v[NH] = {p0.x + aD[0], p0.y + aD[1], p1.x + aD[2],
                     p1.y + aD[3], p2.x + aD[4], p2.y + aD[5]};
      float mm[NH], w[NH], ss[NH];
      #pragma unroll
      for (int h = 0; h < NH; ++h) {
        v[h] = (v[h] > 0.f) ? v[h] : NEG * v[h];
        mm[h] = val ? v[h] : -1e30f;
      }
      #pragma unroll
      for (int h = 0; h < NH; ++h)
        #pragma unroll
        for (int off = 32; off > 0; off >>= 1)
          mm[h] = fmaxf(mm[h], __shfl_xor(mm[h], off));
      #pragma unroll
      for (int h = 0; h < NH; ++h) {
        w[h] = val ? __expf(v[h] - mm[h]) : 0.f;
        ss[h] = w[h];
      }
      #pragma unroll
      for (int h = 0; h < NH; ++h)
        #pragma unroll
        for (int off = 32; off > 0; off >>= 1)
          ss[h] += __shfl_xor(ss[h], off);
      #pragma unroll
      for (int h = 0; h < NH; ++h)
        l_wf[wv][b][h][lane] = w[h] * __frcp_rn(ss[h] + 1e-16f);
    }
  } else {
    // generic slow path (wave-uniform branch; statistically never taken)
    #pragma unroll
    for (int b = 0; b < 2; ++b) {
      const int layer = (lvl ? 1 : 0) + (b ? 2 : 0);
      const float* aS = g_alS[layer];
      const float* aD = g_alD[layer] + (size_t)node * NH;
      float ad[NH];
      #pragma unroll
      for (int h = 0; h < NH; ++h) ad[h] = aD[h];
      #pragma unroll
      for (int h = 0; h < NH; ++h) m[b][h] = -1e30f;
      for (int e = lo + lane; e < hi; e += 64) {
        int se = g_colsrc[e];
        #pragma unroll
        for (int h = 0; h < NH; ++h) {
          float v = aS[se * NH + h] + ad[h];
          v = (v > 0.f) ? v : NEG * v;
          m[b][h] = fmaxf(m[b][h], v);
        }
      }
      #pragma unroll
      for (int h = 0; h < NH; ++h)
        #pragma unroll
        for (int off = 32; off > 0; off >>= 1)
          m[b][h] = fmaxf(m[b][h], __shfl_xor(m[b][h], off));
      float ss[NH] = {0.f, 0.f, 0.f, 0.f, 0.f, 0.f};
      for (int e = lo + lane; e < hi; e += 64) {
        int se = g_colsrc[e];
        #pragma unroll
        for (int h = 0; h < NH; ++h) {
          float v = aS[se * NH + h] + ad[h];
          v = (v > 0.f) ? v : NEG * v;
          ss[h] += __expf(v - m[b][h]);
        }
      }
      #pragma unroll
      for (int h = 0; h < NH; ++h) {
        #pragma unroll
        for (int off = 32; off > 0; off >>= 1)
          ss[h] += __shfl_xor(ss[h], off);
        inv[b][h] = __frcp_rn(ss[h] + 1e-16f);
      }
    }
  }

  // pass 2: lane owns dims {c*128+2*lane, +1}, c=0..2; head = 2c + hiHalf.
  float2 aA[2][3] = {};
  float2 aB[2][3] = {};

  if (fast) {
    const int h0 = hiHalf ? 1 : 0, h1 = hiHalf ? 3 : 2, h2 = hiHalf ? 5 : 4;
    const int degR = (deg + 3) & ~3;   // rounded; extras are zero-weight
    for (int e = 0; e < degR; e += 4) {
      int4 se4 = *(int4*)&l_se[wv][e];
      float4 w00 = *(float4*)&l_wf[wv][0][h0][e];
      float4 w01 = *(float4*)&l_wf[wv][0][h1][e];
      float4 w02 = *(float4*)&l_wf[wv][0][h2][e];
      float4 w10 = *(float4*)&l_wf[wv][1][h0][e];
      float4 w11 = *(float4*)&l_wf[wv][1][h1][e];
      float4 w12 = *(float4*)&l_wf[wv][1][h2][e];
      const unsigned* r0 = (const unsigned*)(g_h16[0] + (size_t)se4.x * FF) + lane;
      const unsigned* r1 = (const unsigned*)(g_h16[0] + (size_t)se4.y * FF) + lane;
      const unsigned* r2 = (const unsigned*)(g_h16[0] + (size_t)se4.z * FF) + lane;
      const unsigned* r3 = (const unsigned*)(g_h16[0] + (size_t)se4.w * FF) + lane;
      // branch-0 rows
      unsigned a0[3] = {r0[0], r0[64], r0[128]};
      unsigned a1[3] = {r1[0], r1[64], r1[128]};
      unsigned a2[3] = {r2[0], r2[64], r2[128]};
      unsigned a3[3] = {r3[0], r3[64], r3[128]};
      // branch-1 rows at constant offset
      unsigned b0[3] = {r0[TBLOFF], r0[TBLOFF + 64], r0[TBLOFF + 128]};
      unsigned b1[3] = {r1[TBLOFF], r1[TBLOFF + 64], r1[TBLOFF + 128]};
      unsigned b2[3] = {r2[TBLOFF], r2[TBLOFF + 64], r2[TBLOFF + 128]};
      unsigned b3[3] = {r3[TBLOFF], r3[TBLOFF + 64], r3[TBLOFF + 128]};
      fmix(aA[0][0], a0[0], w00.x); fmix(aB[0][0], a1[0], w00.y);
      fmix(aA[0][0], a2[0], w00.z); fmix(aB[0][0], a3[0], w00.w);
      fmix(aA[0][1], a0[1], w01.x); fmix(aB[0][1], a1[1], w01.y);
      fmix(aA[0][1], a2[1], w01.z); fmix(aB[0][1], a3[1], w01.w);
      fmix(aA[0][2], a0[2], w02.x); fmix(aB[0][2], a1[2], w02.y);
      fmix(aA[0][2], a2[2], w02.z); fmix(aB[0][2], a3[2], w02.w);
      fmix(aA[1][0], b0[0], w10.x); fmix(aB[1][0], b1[0], w10.y);
      fmix(aA[1][0], b2[0], w10.z); fmix(aB[1][0], b3[0], w10.w);
      fmix(aA[1][1], b0[1], w11.x); fmix(aB[1][1], b1[1], w11.y);
      fmix(aA[1][1], b2[1], w11.z); fmix(aB[1][1], b3[1], w11.w);
      fmix(aA[1][2], b0[2], w12.x); fmix(aB[1][2], b1[2], w12.y);
      fmix(aA[1][2], b2[2], w12.z); fmix(aB[1][2], b3[2], w12.w);
    }
  } else {
    for (int e = 0; e < deg; ++e) {
      int se = g_colsrc[lo + e];
      const unsigned* r0 = (const unsigned*)(g_h16[0] + (size_t)se * FF) + lane;
      unsigned av[3] = {r0[0], r0[64], r0[128]};
      unsigned bv[3] = {r0[TBLOFF], r0[TBLOFF + 64], r0[TBLOFF + 128]};
      #pragma unroll
      for (int b = 0; b < 2; ++b) {
        const int layer = (lvl ? 1 : 0) + (b ? 2 : 0);
        const float* as = g_alS[layer] + (size_t)se * NH;
        const float* aD = g_alD[layer] + (size_t)node * NH;
        float we[NH];
        #pragma unroll
        for (int h = 0; h < NH; ++h) {
          float v = as[h] + aD[h];
          v = (v > 0.f) ? v : NEG * v;
          we[h] = __expf(v - m[b][h]) * inv[b][h];
        }
        float wa[3] = {hiHalf ? we[1] : we[0], hiHalf ? we[3] : we[2],
                       hiHalf ? we[5] : we[4]};
        const unsigned* rv = b ? bv : av;
        #pragma unroll
        for (int c = 0; c < 3; ++c) fmix(aA[b][c], rv[c], wa[c]);
      }
    }
  }

  #pragma unroll
  for (int b = 0; b < 2; ++b) {
    const float* bias = b ? bias1 : bias0;
    #pragma unroll
    for (int c = 0; c < 3; ++c) {
      float2 bv = *(const float2*)(bias + c * 128 + lane * 2);
      float ox = fmaxf(aA[b][c].x + aB[b][c].x + bv.x, 0.f);
      float oy = fmaxf(aA[b][c].y + aB[b][c].y + bv.y, 0.f);
      size_t off = (size_t)node * FF + c * 128 + lane * 2;
      ushort2 hh2 = {f2bf(ox), f2bf(oy)};
      *(ushort2*)(g_feat[b] + off) = hh2;   // lvl0: GEMM input; lvl1: pool input
    }
  }
}

// ---------------- pooling: segmented accumulation over sorted batch ----------
__global__ __launch_bounds__(384) void k_pool_acc(const int* __restrict__ batch) {
  int n0 = blockIdx.x * PCH;
  if (n0 >= NN) return;
  int n1 = n0 + PCH; if (n1 > NN) n1 = NN;
  int d = threadIdx.x;
  int cur = batch[n0];
  float acc = 0.f;
  int cnt = 0;
  for (int n = n0; n < n1; ++n) {
    int g = batch[n];
    if (g != cur) {
      atomicAdd(&g_pool[cur * FF + d], acc);
      if (d == 0) atomicAdd(&g_gcnt[cur], cnt);
      acc = 0.f; cnt = 0; cur = g;
    }
    acc += bf2f(g_feat[0][(size_t)n * FF + d]) + bf2f(g_feat[1][(size_t)n * FF + d]);
    ++cnt;
  }
  atomicAdd(&g_pool[cur * FF + d], acc);
  if (d == 0) atomicAdd(&g_gcnt[cur], cnt);
}

// ---------------- finish: mean + readout MLP (fused) -------------------------
__global__ __launch_bounds__(384) void k_finish(const float* __restrict__ r1w,
                                                const float* __restrict__ r1b,
                                                const float* __restrict__ r2w,
                                                const float* __restrict__ r2b,
                                                float* __restrict__ dout) {
  int g = blockIdx.x;
  int d = threadIdx.x;
  __shared__ float xr[FF];
  __shared__ float hid[64];
  int cnt = g_gcnt[g];
  float denom = (cnt > 0) ? (float)cnt : 1.f;
  float v = g_pool[g * FF + d] / denom;
  xr[d] = v;
  dout[NG * NOUT + g * FF + d] = v;
  __syncthreads();
  if (d < 64) {
    float acc = r1b[d];
    for (int k = 0; k < FF; ++k) acc = fmaf(xr[k], r1w[k * 64 + d], acc);
    hid[d] = fmaxf(acc, 0.f);
  }
  __syncthreads();
  if (d < NOUT) {
    float o = r2b[d];
    #pragma unroll
    for (int j = 0; j < 64; ++j) o = fmaf(hid[j], r2w[j * NOUT + d], o);
    dout[g * NOUT + d] = o;
  }
}

// ---------------- orchestration ----------------------------------------------
extern "C" void kernel_launch(void* const* d_in, const int* in_sizes, int n_in,
                              void* d_out, int out_size, void* d_ws, size_t ws_size,
                              hipStream_t stream) {
  const float* x    = (const float*)d_in[0];
  const int* ei     = (const int*)d_in[1];
  const int* batch  = (const int*)d_in[2];
  const float* W1   = (const float*)d_in[3];
  const float* a1s  = (const float*)d_in[4];
  const float* a1d  = (const float*)d_in[5];
  const float* b1   = (const float*)d_in[6];
  const float* W2   = (const float*)d_in[7];
  const float* a2s  = (const float*)d_in[8];
  const float* a2d  = (const float*)d_in[9];
  const float* b2   = (const float*)d_in[10];
  const float* Ws1  = (const float*)d_in[11];
  const float* as1s = (const float*)d_in[12];
  const float* as1d = (const float*)d_in[13];
  const float* bs1  = (const float*)d_in[14];
  const float* Ws2  = (const float*)d_in[15];
  const float* as2s = (const float*)d_in[16];
  const float* as2d = (const float*)d_in[17];
  const float* bs2  = (const float*)d_in[18];
  const float* r1w  = (const float*)d_in[19];
  const float* r1b  = (const float*)d_in[20];
  const float* r2w  = (const float*)d_in[21];
  const float* r2b  = (const float*)d_in[22];
  float* out = (float*)d_out;

  dim3 b256(256);
  // merged prep: weight transpose+cast, zeroing, x->bf16
  k_prep<<<dim3(2048), b256, 0, stream>>>(x, Ws1, Ws2, W1, W2);
  k_hist<<<dim3((ETOT + 255) / 256), b256, 0, stream>>>(ei);
  // hierarchical scan
  k_scan_blk<<<dim3(NB), b256, 0, stream>>>();
  k_scan_top<<<dim3(1), dim3(128), 0, stream>>>();
  k_scan_add<<<dim3(NB), b256, 0, stream>>>();
  k_scatter<<<dim3((ETOT + 255) / 256), b256, 0, stream>>>(ei);

  dim3 gemmGrid((NN + 127) / 128, FF / 128, 2);   // z = branch
  dim3 edgeGrid(NBLK);                             // both branches per wave

  // level 1: h16[br] = x @ W (both branches); feat[br] = edge(both branches)
  k_gemm<<<gemmGrid, b256, 0, stream>>>(0, as1s, as1d, a1s, a1d);
  k_edge<<<edgeGrid, b256, 0, stream>>>(0, bs1, b1);
  // level 2: h16[br] = feat[br] @ W (both); feat[br] = edge(both)
  k_gemm<<<gemmGrid, b256, 0, stream>>>(1, as2s, as2d, a2s, a2d);
  k_edge<<<edgeGrid, b256, 0, stream>>>(1, bs2, b2);
  // pool (feat[0] + feat[1]) and readout
  k_pool_acc<<<dim3((NN + PCH - 1) / PCH), dim3(384), 0, stream>>>(batch);
  k_finish<<<dim3(NG), dim3(384), 0, stream>>>(r1w, r1b, r2w, r2b, out);
}

// Round 19
// 311.200 us; speedup vs baseline: 1.1017x; 1.1017x over previous
//
#include <hip/hip_runtime.h>
#include <hip/hip_fp16.h>

#define NN 20000
#define EE 320000
#define ETOT 340000
#define FIN 128
#define NH 6
#define FF 384
#define NOUT 10
#define NG 64
#define NEG 0.2f
#define PCH 32
#define NB ((NN + 255) / 256)
#define NBLK ((NN + 3) / 4)

typedef short short8 __attribute__((ext_vector_type(8)));
typedef float f32x4 __attribute__((ext_vector_type(4)));

// ---------------- static device storage (avoids ws_size dependence) ----------
__device__ __half g_h16[2][(size_t)NN * FF];          // per-branch h tables
__device__ unsigned short g_feat[2][(size_t)NN * FF]; // bf16 L1-out, reused as L2-out
__device__ unsigned short g_xHi[(size_t)NN * FIN];
__device__ unsigned short g_WtHi[4][FF * FF];  // transposed weights [col][k]
__device__ float g_alS[4][NN * NH];            // per-layer alpha_src (atomic acc)
__device__ float g_alD[4][NN * NH];
__device__ int g_rowptr[NN + 1];
__device__ int g_cnt[NN];
__device__ int g_cur[NN];
__device__ int g_blocksum[NB];
__device__ int g_colsrc[ETOT];
__device__ float g_pool[NG * FF];
__device__ int g_gcnt[NG];

// ---------------- helpers ----------------------------------------------------
__device__ __forceinline__ unsigned short f2bf(float f) {
  unsigned u = __float_as_uint(f);
  u += 0x7FFFu + ((u >> 16) & 1u);
  return (unsigned short)(u >> 16);
}
__device__ __forceinline__ float bf2f(unsigned short s) {
  return __uint_as_float(((unsigned)s) << 16);
}

__device__ __forceinline__ void gl_lds16(const void* g, void* l) {
  __builtin_amdgcn_global_load_lds(
      (const __attribute__((address_space(1))) unsigned int*)(unsigned long long)g,
      (__attribute__((address_space(3))) unsigned int*)(unsigned int)(unsigned long long)l,
      16, 0, 0);
}

__device__ __forceinline__ void mfma_acc(f32x4& c, short8 a, short8 b) {
  asm("v_mfma_f32_16x16x32_bf16 %0, %1, %2, %0" : "+v"(c) : "v"(a), "v"(b));
}

// fp16-source FMA into f32 acc: acc.x += f16lo(hv)*w ; acc.y += f16hi(hv)*w
__device__ __forceinline__ void fmix(float2& acc, unsigned hv, float w) {
  asm("v_fma_mix_f32 %0, %2, %3, %0 op_sel:[0,0,0] op_sel_hi:[1,0,0]\n\t"
      "v_fma_mix_f32 %1, %2, %3, %1 op_sel:[1,0,0] op_sel_hi:[1,0,0]"
      : "+v"(acc.x), "+v"(acc.y)
      : "v"(hv), "v"(w));
}

// ---------------- merged prep: weight bf16-transpose + zeroing + x->bf16 -----
__global__ __launch_bounds__(256) void k_prep(const float* __restrict__ xin,
                                              const float* __restrict__ Ws1,
                                              const float* __restrict__ Ws2,
                                              const float* __restrict__ W1,
                                              const float* __restrict__ W2) {
  const int tid = blockIdx.x * 256 + threadIdx.x;
  const int stride = gridDim.x * 256;
  for (int i = tid; i < FIN * FF; i += stride) {
    int k = i / FF, c = i % FF;
    g_WtHi[0][c * FIN + k] = f2bf(Ws1[i]);
    g_WtHi[2][c * FIN + k] = f2bf(W1[i]);
  }
  for (int i = tid; i < FF * FF; i += stride) {
    int k = i / FF, c = i % FF;
    g_WtHi[1][c * FF + k] = f2bf(Ws2[i]);
    g_WtHi[3][c * FF + k] = f2bf(W2[i]);
  }
  for (int i = tid; i < NN; i += stride) g_cnt[i] = 0;
  for (int i = tid; i < NG * FF; i += stride) g_pool[i] = 0.f;
  for (int i = tid; i < NG; i += stride) g_gcnt[i] = 0;
  for (int i = tid; i < 4 * NN * NH; i += stride) {
    (&g_alS[0][0])[i] = 0.f;
    (&g_alD[0][0])[i] = 0.f;
  }
  const float4* s4 = (const float4*)xin;
  ushort4* oh4 = (ushort4*)g_xHi;
  for (int i = tid; i < (NN * FIN) >> 2; i += stride) {
    float4 v = s4[i];
    ushort4 h;
    h.x = f2bf(v.x); h.y = f2bf(v.y); h.z = f2bf(v.z); h.w = f2bf(v.w);
    oh4[i] = h;
  }
}

__global__ __launch_bounds__(256) void k_hist(const int* __restrict__ ei) {
  int i = blockIdx.x * 256 + threadIdx.x;
  if (i >= ETOT) return;
  int d = (i < EE) ? ei[EE + i] : (i - EE);
  atomicAdd(&g_cnt[d], 1);
}

// ---------------- hierarchical scan (3 launches, shuffle-based) --------------
__global__ __launch_bounds__(256) void k_scan_blk() {
  int b = blockIdx.x;
  int tid = threadIdx.x;
  int i = b * 256 + tid;
  int lane = tid & 63, wid = tid >> 6;
  int v = (i < NN) ? g_cnt[i] : 0;
  int s = v;
  #pragma unroll
  for (int off = 1; off < 64; off <<= 1) {
    int t = __shfl_up(s, off);
    if (lane >= off) s += t;
  }
  __shared__ int wsum[4];
  if (lane == 63) wsum[wid] = s;
  __syncthreads();
  int woff = 0;
  #pragma unroll
  for (int w = 0; w < 4; ++w) woff += (w < wid) ? wsum[w] : 0;
  if (i < NN) g_rowptr[i] = woff + s - v;   // block-local exclusive
  if (tid == 0) g_blocksum[b] = wsum[0] + wsum[1] + wsum[2] + wsum[3];
}

__global__ __launch_bounds__(128) void k_scan_top() {
  int tid = threadIdx.x;
  int lane = tid & 63, wid = tid >> 6;
  int v = (tid < NB) ? g_blocksum[tid] : 0;
  int s = v;
  #pragma unroll
  for (int off = 1; off < 64; off <<= 1) {
    int t = __shfl_up(s, off);
    if (lane >= off) s += t;
  }
  __shared__ int wsum[2];
  if (lane == 63) wsum[wid] = s;
  __syncthreads();
  int woff = (wid == 1) ? wsum[0] : 0;
  int excl = woff + s - v;
  if (tid < NB) g_blocksum[tid] = excl;
  if (tid == NB - 1) g_rowptr[NN] = excl + v;
}

__global__ __launch_bounds__(256) void k_scan_add() {
  int i = blockIdx.x * 256 + threadIdx.x;
  if (i >= NN) return;
  int r = g_rowptr[i] + g_blocksum[blockIdx.x];
  g_rowptr[i] = r;
  g_cur[i] = r;
}

__global__ __launch_bounds__(256) void k_scatter(const int* __restrict__ ei) {
  int i = blockIdx.x * 256 + threadIdx.x;
  if (i >= ETOT) return;
  int s, d;
  if (i < EE) { s = ei[i]; d = ei[EE + i]; } else { s = d = i - EE; }
  int pos = atomicAdd(&g_cur[d], 1);
  g_colsrc[pos] = s;
}

// ---------------- GEMM: h16[br] = A @ WtHi^T (single-term bf16, fp32 acc) ----
// both branches of one level in one launch (blockIdx.z = branch).
// epilogue: fused alpha partials (each wave's 64-col stripe = one head).
__global__ __launch_bounds__(256) void k_gemm(int lvl,
                                              const float* __restrict__ asr0,
                                              const float* __restrict__ adt0,
                                              const float* __restrict__ asr1,
                                              const float* __restrict__ adt1) {
  __shared__ unsigned short lA[128 * 64];
  __shared__ unsigned short lB[128 * 64];
  const int br = blockIdx.z;
  const int layer = (lvl ? 1 : 0) + (br ? 2 : 0);
  const int widx = layer;                 // 0=Ws1,1=Ws2,2=W1,3=W2
  const int K = lvl ? FF : FIN;
  const unsigned short* Ah = lvl ? g_feat[br] : g_xHi;
  const unsigned short* Bh = g_WtHi[widx];
  const float* asr = br ? asr1 : asr0;
  const float* adt = br ? adt1 : adt0;
  __half* hout = g_h16[br];
  const int m0 = blockIdx.x * 128;
  const int n0 = blockIdx.y * 128;
  const int tid = threadIdx.x;
  const int wave = tid >> 6, lane = tid & 63;
  const int wm = wave >> 1, wn = wave & 1;
  const int srow = lane >> 3;        // row within 8-row chunk
  const int scol = (lane & 7) * 8;   // k-element offset

  f32x4 acc[4][4] = {};

  for (int k0 = 0; k0 < K; k0 += 64) {
    __syncthreads();  // prior reads done before overwrite
    #pragma unroll
    for (int it = 0; it < 4; ++it) {
      int c = wave * 4 + it;
      int rA = c * 8 + srow;
      int gr = m0 + rA; gr = (gr < NN) ? gr : (NN - 1);
      gl_lds16(Ah + (size_t)gr * K + k0 + scol, (unsigned short*)lA + c * 512);
      int cB = n0 + rA;  // always < 384
      gl_lds16(Bh + (size_t)cB * K + k0 + scol, (unsigned short*)lB + c * 512);
    }
    __syncthreads();  // drains vmcnt for global_load_lds
    #pragma unroll
    for (int kk = 0; kk < 64; kk += 32) {
      const int kb = kk + (lane >> 4) * 8;
      const int r16 = lane & 15;
      short8 af[4], bfr[4];
      #pragma unroll
      for (int mf = 0; mf < 4; ++mf)
        af[mf] = *(const short8*)&lA[(wm * 64 + mf * 16 + r16) * 64 + kb];
      #pragma unroll
      for (int nf = 0; nf < 4; ++nf)
        bfr[nf] = *(const short8*)&lB[(wn * 64 + nf * 16 + r16) * 64 + kb];
      #pragma unroll
      for (int mf = 0; mf < 4; ++mf)
        #pragma unroll
        for (int nf = 0; nf < 4; ++nf)
          mfma_acc(acc[mf][nf], af[mf], bfr[nf]);
    }
  }
  asm volatile("s_nop 7\n\ts_nop 7" :::);

  const int r16 = lane & 15;
  // ---- C-write (fp16 table) ----
  #pragma unroll
  for (int mf = 0; mf < 4; ++mf) {
    #pragma unroll
    for (int nf = 0; nf < 4; ++nf) {
      int col = n0 + wn * 64 + nf * 16 + r16;
      int rb = m0 + wm * 64 + mf * 16 + ((lane >> 4) << 2);
      #pragma unroll
      for (int j = 0; j < 4; ++j) {
        int r = rb + j;
        if (r < NN) hout[(size_t)r * FF + col] = __float2half(acc[mf][nf][j]);
      }
    }
  }
  // ---- fused alpha partials: head = by*2 + wn ----
  const int hd = blockIdx.y * 2 + wn;
  float as_v[4], ad_v[4];
  #pragma unroll
  for (int nf = 0; nf < 4; ++nf) {
    as_v[nf] = asr[hd * 64 + nf * 16 + r16];
    ad_v[nf] = adt[hd * 64 + nf * 16 + r16];
  }
  float* alS = g_alS[layer];
  float* alD = g_alD[layer];
  #pragma unroll
  for (int mf = 0; mf < 4; ++mf) {
    #pragma unroll
    for (int j = 0; j < 4; ++j) {
      float ps = 0.f, pd = 0.f;
      #pragma unroll
      for (int nf = 0; nf < 4; ++nf) {
        ps = fmaf(acc[mf][nf][j], as_v[nf], ps);
        pd = fmaf(acc[mf][nf][j], ad_v[nf], pd);
      }
      #pragma unroll
      for (int off = 1; off < 16; off <<= 1) {
        ps += __shfl_xor(ps, off);
        pd += __shfl_xor(pd, off);
      }
      int r = m0 + wm * 64 + mf * 16 + ((lane >> 4) << 2) + j;
      if (r16 == 0 && r < NN) {
        atomicAdd(&alS[r * NH + hd], ps);
        atomicAdd(&alD[r * NH + hd], pd);
      }
    }
  }
}

// ---------------- softmax + aggregation, one wave per destination node -------
// both branches of one level in one launch (blockIdx.y = branch).
// fast path: lane-parallel softmax; sources + per-head f32 weights staged in
// per-wave LDS (broadcast reads, no shuffles); pass-2 x4, tail-free.
// lvl 0: out -> g_feat[br] (bf16, GEMM input). lvl 1: out -> g_feat[br] (bf16, pool input).
__global__ __launch_bounds__(256) void k_edge(int lvl,
                                              const float* __restrict__ bias0,
                                              const float* __restrict__ bias1) {
  __shared__ int l_se[4][64];
  __shared__ float l_wf[4][NH][64];
  int wv = threadIdx.x >> 6;
  int node = blockIdx.x * 4 + wv;
  int lane = threadIdx.x & 63;
  if (node >= NN) return;
  const int br = blockIdx.y;
  const int layer = (lvl ? 1 : 0) + (br ? 2 : 0);
  const float* bias = br ? bias1 : bias0;
  const __half* htab = g_h16[br];
  const float* aS = g_alS[layer];
  const float* aD = g_alD[layer];
  const int lo = g_rowptr[node], hi = g_rowptr[node + 1];
  const int deg = hi - lo;
  float ad[NH];
  #pragma unroll
  for (int h = 0; h < NH; ++h) ad[h] = aD[node * NH + h];

  const bool hiHalf = (lane >= 32);
  float m[NH], inv[NH];      // slow-path state
  const bool fast = (deg <= 64);

  if (fast) {
    bool val = lane < deg;
    int s = val ? g_colsrc[lo + lane] : 0;
    const float2* ap = (const float2*)(aS + (size_t)s * NH);
    float2 p0 = ap[0], p1 = ap[1], p2 = ap[2];
    float v[NH] = {p0.x + ad[0], p0.y + ad[1], p1.x + ad[2],
                   p1.y + ad[3], p2.x + ad[4], p2.y + ad[5]};
    float mm[NH], w[NH], ss[NH];
    #pragma unroll
    for (int h = 0; h < NH; ++h) {
      v[h] = (v[h] > 0.f) ? v[h] : NEG * v[h];
      mm[h] = val ? v[h] : -1e30f;
    }
    #pragma unroll
    for (int h = 0; h < NH; ++h)
      #pragma unroll
      for (int off = 32; off > 0; off >>= 1)
        mm[h] = fmaxf(mm[h], __shfl_xor(mm[h], off));
    #pragma unroll
    for (int h = 0; h < NH; ++h) {
      w[h] = val ? __expf(v[h] - mm[h]) : 0.f;
      ss[h] = w[h];
    }
    #pragma unroll
    for (int h = 0; h < NH; ++h)
      #pragma unroll
      for (int off = 32; off > 0; off >>= 1)
        ss[h] += __shfl_xor(ss[h], off);
    // stage source + per-head normalized f32 weights in per-wave LDS
    l_se[wv][lane] = s;
    #pragma unroll
    for (int h = 0; h < NH; ++h)
      l_wf[wv][h][lane] = w[h] * __frcp_rn(ss[h] + 1e-16f);
  } else {
    // generic slow path (wave-uniform branch; statistically never taken)
    #pragma unroll
    for (int h = 0; h < NH; ++h) m[h] = -1e30f;
    for (int e = lo + lane; e < hi; e += 64) {
      int se = g_colsrc[e];
      #pragma unroll
      for (int h = 0; h < NH; ++h) {
        float v = aS[se * NH + h] + ad[h];
        v = (v > 0.f) ? v : NEG * v;
        m[h] = fmaxf(m[h], v);
      }
    }
    #pragma unroll
    for (int h = 0; h < NH; ++h)
      #pragma unroll
      for (int off = 32; off > 0; off >>= 1)
        m[h] = fmaxf(m[h], __shfl_xor(m[h], off));
    float ss[NH] = {0.f, 0.f, 0.f, 0.f, 0.f, 0.f};
    for (int e = lo + lane; e < hi; e += 64) {
      int se = g_colsrc[e];
      #pragma unroll
      for (int h = 0; h < NH; ++h) {
        float v = aS[se * NH + h] + ad[h];
        v = (v > 0.f) ? v : NEG * v;
        ss[h] += __expf(v - m[h]);
      }
    }
    #pragma unroll
    for (int h = 0; h < NH; ++h) {
      #pragma unroll
      for (int off = 32; off > 0; off >>= 1)
        ss[h] += __shfl_xor(ss[h], off);
      inv[h] = __frcp_rn(ss[h] + 1e-16f);
    }
  }

  // pass 2: weighted aggregation. lane owns dims {c*128+2*lane, +1}, c=0..2.
  // this lane's head for chunk c is 2c + hiHalf.
  float2 accA[3] = {{0.f,0.f},{0.f,0.f},{0.f,0.f}};
  float2 accB[3] = {{0.f,0.f},{0.f,0.f},{0.f,0.f}};
  float2 accC[3] = {{0.f,0.f},{0.f,0.f},{0.f,0.f}};
  float2 accD[3] = {{0.f,0.f},{0.f,0.f},{0.f,0.f}};

  if (fast) {
    const int h0 = hiHalf ? 1 : 0, h1 = hiHalf ? 3 : 2, h2 = hiHalf ? 5 : 4;
    const int degR = (deg + 3) & ~3;   // rounded; extra entries are zero-weight
    for (int e = 0; e < degR; e += 4) {
      int4 se4 = *(int4*)&l_se[wv][e];
      float4 w0 = *(float4*)&l_wf[wv][h0][e];
      float4 w1 = *(float4*)&l_wf[wv][h1][e];
      float4 w2 = *(float4*)&l_wf[wv][h2][e];
      const unsigned* r0 = (const unsigned*)(htab + (size_t)se4.x * FF) + lane;
      const unsigned* r1 = (const unsigned*)(htab + (size_t)se4.y * FF) + lane;
      const unsigned* r2 = (const unsigned*)(htab + (size_t)se4.z * FF) + lane;
      const unsigned* r3 = (const unsigned*)(htab + (size_t)se4.w * FF) + lane;
      unsigned ha[3] = {r0[0], r0[64], r0[128]};
      unsigned hb[3] = {r1[0], r1[64], r1[128]};
      unsigned hc[3] = {r2[0], r2[64], r2[128]};
      unsigned hd[3] = {r3[0], r3[64], r3[128]};
      fmix(accA[0], ha[0], w0.x); fmix(accB[0], hb[0], w0.y);
      fmix(accC[0], hc[0], w0.z); fmix(accD[0], hd[0], w0.w);
      fmix(accA[1], ha[1], w1.x); fmix(accB[1], hb[1], w1.y);
      fmix(accC[1], hc[1], w1.z); fmix(accD[1], hd[1], w1.w);
      fmix(accA[2], ha[2], w2.x); fmix(accB[2], hb[2], w2.y);
      fmix(accC[2], hc[2], w2.z); fmix(accD[2], hd[2], w2.w);
    }
  } else {
    for (int e = 0; e < deg; ++e) {
      int se = g_colsrc[lo + e];
      const float* as = aS + (size_t)se * NH;
      float we[NH];
      #pragma unroll
      for (int h = 0; h < NH; ++h) {
        float v = as[h] + ad[h];
        v = (v > 0.f) ? v : NEG * v;
        we[h] = __expf(v - m[h]) * inv[h];
      }
      float wa[3] = {hiHalf ? we[1] : we[0], hiHalf ? we[3] : we[2],
                     hiHalf ? we[5] : we[4]};
      const unsigned* r0 = (const unsigned*)(htab + (size_t)se * FF) + lane;
      unsigned h0v[3] = {r0[0], r0[64], r0[128]};
      #pragma unroll
      for (int c = 0; c < 3; ++c) fmix(accA[c], h0v[c], wa[c]);
    }
  }

  #pragma unroll
  for (int c = 0; c < 3; ++c) {
    float2 bv = *(const float2*)(bias + c * 128 + lane * 2);
    float ox = fmaxf(accA[c].x + accB[c].x + accC[c].x + accD[c].x + bv.x, 0.f);
    float oy = fmaxf(accA[c].y + accB[c].y + accC[c].y + accD[c].y + bv.y, 0.f);
    size_t off = (size_t)node * FF + c * 128 + lane * 2;
    ushort2 hh2 = {f2bf(ox), f2bf(oy)};
    *(ushort2*)(g_feat[br] + off) = hh2;   // lvl0: GEMM input; lvl1: pool input
  }
}

// ---------------- pooling: segmented accumulation over sorted batch ----------
__global__ __launch_bounds__(384) void k_pool_acc(const int* __restrict__ batch) {
  int n0 = blockIdx.x * PCH;
  if (n0 >= NN) return;
  int n1 = n0 + PCH; if (n1 > NN) n1 = NN;
  int d = threadIdx.x;
  int cur = batch[n0];
  float acc = 0.f;
  int cnt = 0;
  for (int n = n0; n < n1; ++n) {
    int g = batch[n];
    if (g != cur) {
      atomicAdd(&g_pool[cur * FF + d], acc);
      if (d == 0) atomicAdd(&g_gcnt[cur], cnt);
      acc = 0.f; cnt = 0; cur = g;
    }
    acc += bf2f(g_feat[0][(size_t)n * FF + d]) + bf2f(g_feat[1][(size_t)n * FF + d]);
    ++cnt;
  }
  atomicAdd(&g_pool[cur * FF + d], acc);
  if (d == 0) atomicAdd(&g_gcnt[cur], cnt);
}

// ---------------- finish: mean + readout MLP (fused) -------------------------
__global__ __launch_bounds__(384) void k_finish(const float* __restrict__ r1w,
                                                const float* __restrict__ r1b,
                                                const float* __restrict__ r2w,
                                                const float* __restrict__ r2b,
                                                float* __restrict__ dout) {
  int g = blockIdx.x;
  int d = threadIdx.x;
  __shared__ float xr[FF];
  __shared__ float hid[64];
  int cnt = g_gcnt[g];
  float denom = (cnt > 0) ? (float)cnt : 1.f;
  float v = g_pool[g * FF + d] / denom;
  xr[d] = v;
  dout[NG * NOUT + g * FF + d] = v;
  __syncthreads();
  if (d < 64) {
    float acc = r1b[d];
    for (int k = 0; k < FF; ++k) acc = fmaf(xr[k], r1w[k * 64 + d], acc);
    hid[d] = fmaxf(acc, 0.f);
  }
  __syncthreads();
  if (d < NOUT) {
    float o = r2b[d];
    #pragma unroll
    for (int j = 0; j < 64; ++j) o = fmaf(hid[j], r2w[j * NOUT + d], o);
    dout[g * NOUT + d] = o;
  }
}

// ---------------- orchestration ----------------------------------------------
extern "C" void kernel_launch(void* const* d_in, const int* in_sizes, int n_in,
                              void* d_out, int out_size, void* d_ws, size_t ws_size,
                              hipStream_t stream) {
  const float* x    = (const float*)d_in[0];
  const int* ei     = (const int*)d_in[1];
  const int* batch  = (const int*)d_in[2];
  const float* W1   = (const float*)d_in[3];
  const float* a1s  = (const float*)d_in[4];
  const float* a1d  = (const float*)d_in[5];
  const float* b1   = (const float*)d_in[6];
  const float* W2   = (const float*)d_in[7];
  const float* a2s  = (const float*)d_in[8];
  const float* a2d  = (const float*)d_in[9];
  const float* b2   = (const float*)d_in[10];
  const float* Ws1  = (const float*)d_in[11];
  const float* as1s = (const float*)d_in[12];
  const float* as1d = (const float*)d_in[13];
  const float* bs1  = (const float*)d_in[14];
  const float* Ws2  = (const float*)d_in[15];
  const float* as2s = (const float*)d_in[16];
  const float* as2d = (const float*)d_in[17];
  const float* bs2  = (const float*)d_in[18];
  const float* r1w  = (const float*)d_in[19];
  const float* r1b  = (const float*)d_in[20];
  const float* r2w  = (const float*)d_in[21];
  const float* r2b  = (const float*)d_in[22];
  float* out = (float*)d_out;

  dim3 b256(256);
  // merged prep: weight transpose+cast, zeroing, x->bf16
  k_prep<<<dim3(2048), b256, 0, stream>>>(x, Ws1, Ws2, W1, W2);
  k_hist<<<dim3((ETOT + 255) / 256), b256, 0, stream>>>(ei);
  // hierarchical scan
  k_scan_blk<<<dim3(NB), b256, 0, stream>>>();
  k_scan_top<<<dim3(1), dim3(128), 0, stream>>>();
  k_scan_add<<<dim3(NB), b256, 0, stream>>>();
  k_scatter<<<dim3((ETOT + 255) / 256), b256, 0, stream>>>(ei);

  dim3 gemmGrid((NN + 127) / 128, FF / 128, 2);   // z = branch
  dim3 edgeGrid(NBLK, 2);                          // y = branch

  // level 1 (both branches): h16[br] = x @ W; feat[br] = edge(...)
  k_gemm<<<gemmGrid, b256, 0, stream>>>(0, as1s, as1d, a1s, a1d);
  k_edge<<<edgeGrid, b256, 0, stream>>>(0, bs1, b1);
  // level 2 (both branches): h16[br] = feat[br] @ W; feat[br] = edge(...)
  k_gemm<<<gemmGrid, b256, 0, stream>>>(1, as2s, as2d, a2s, a2d);
  k_edge<<<edgeGrid, b256, 0, stream>>>(1, bs2, b2);
  // pool (feat[0] + feat[1]) and readout
  k_pool_acc<<<dim3((NN + PCH - 1) / PCH), dim3(384), 0, stream>>>(batch);
  k_finish<<<dim3(NG), dim3(384), 0, stream>>>(r1w, r1b, r2w, r2b, out);
}